// Round 9
// baseline (3098.153 us; speedup 1.0000x reference)
//
#include <hip/hip_runtime.h>
#include <math.h>

#define LSEQ 2048
#define DMODEL 1024
#define NLAYER 12
#define NVOCAB 50257
#define NPADV 50304          /* 393 * 128 */
#define EDIM 2048
#define NST 16
#define DTRANK 64
#define EPSV 1e-5f
#define NCHUNK 64
#define TCHUNK 32   /* LSEQ / NCHUNK */

typedef __attribute__((ext_vector_type(4))) float float4v;
typedef __attribute__((ext_vector_type(8))) short short8v;
typedef __attribute__((ext_vector_type(4))) unsigned short ushort4v;
typedef unsigned short u16;

__device__ __forceinline__ u16 f2bf(float f) {
    union { float f; unsigned int u; } v; v.f = f;
    unsigned int r = v.u + 0x7FFFu + ((v.u >> 16) & 1u);   // RNE
    return (u16)(r >> 16);
}

__device__ __forceinline__ ushort4v cvt4(float4 a) {
    ushort4v r; r[0] = f2bf(a.x); r[1] = f2bf(a.y); r[2] = f2bf(a.z); r[3] = f2bf(a.w);
    return r;
}

__device__ __forceinline__ float4v mfma_bf16(short8v a, short8v b, float4v c) {
    return __builtin_amdgcn_mfma_f32_16x16x32_bf16(a, b, c, 0, 0, 0);
}

// async global->LDS, 16 B per lane; LDS dest = wave-uniform base + lane*16
__device__ __forceinline__ void gload_lds16(const void* g, void* l) {
    __builtin_amdgcn_global_load_lds(
        (const __attribute__((address_space(1))) unsigned int*)g,
        (__attribute__((address_space(3))) unsigned int*)l,
        16, 0, 0);
}

// ---------------- embedding gather ----------------
__global__ __launch_bounds__(256) void k_embed(const int* __restrict__ ids,
                                               const float* __restrict__ emb,
                                               float* __restrict__ res) {
    const int t = blockIdx.x;
    const int row = ids[t];
    ((float4*)(res + (size_t)t * DMODEL))[threadIdx.x] =
        ((const float4*)(emb + (size_t)row * DMODEL))[threadIdx.x];
}

// ---------------- residual add + rmsnorm -> bf16 h ----------------
template<bool ADD>
__global__ __launch_bounds__(256) void k_addnorm(float* __restrict__ res,
                                                 const float* __restrict__ xin,
                                                 const float* __restrict__ w,
                                                 u16* __restrict__ h) {
    const int t = blockIdx.x;
    const int i = threadIdx.x;
    float4 r = ((float4*)(res + (size_t)t * DMODEL))[i];
    if (ADD) {
        float4 xv = ((const float4*)(xin + (size_t)t * DMODEL))[i];
        r.x += xv.x; r.y += xv.y; r.z += xv.z; r.w += xv.w;
        ((float4*)(res + (size_t)t * DMODEL))[i] = r;
    }
    float ss = r.x * r.x + r.y * r.y + r.z * r.z + r.w * r.w;
#pragma unroll
    for (int off = 32; off > 0; off >>= 1) ss += __shfl_xor(ss, off);
    __shared__ float part[4];
    if ((i & 63) == 0) part[i >> 6] = ss;
    __syncthreads();
    float tot = part[0] + part[1] + part[2] + part[3];
    const float inv = rsqrtf(tot * (1.f / DMODEL) + EPSV);
    float4 wv = ((const float4*)w)[i];
    float4 o;
    o.x = r.x * inv * wv.x; o.y = r.y * inv * wv.y;
    o.z = r.z * inv * wv.z; o.w = r.w * inv * wv.w;
    ((ushort4v*)(h + (size_t)t * DMODEL))[i] = cvt4(o);
}

// ---------------- fp32 -> bf16 weight conversion (with zero pad) ----------------
__global__ __launch_bounds__(256) void k_cvt(const float* __restrict__ s, u16* __restrict__ d,
                                             long long n, long long ntot) {
    const long long stride = (long long)gridDim.x * 256 * 8;
    for (long long i = ((long long)blockIdx.x * 256 + threadIdx.x) * 8; i < ntot; i += stride) {
        ushort4v lo, hi;
        if (i < n) {   // n is a multiple of 8, no straddle
            float4 a = *(const float4*)(s + i);
            float4 b = *(const float4*)(s + i + 4);
            lo = cvt4(a); hi = cvt4(b);
        } else {
            lo[0] = lo[1] = lo[2] = lo[3] = 0;
            hi[0] = hi[1] = hi[2] = hi[3] = 0;
        }
        *(ushort4v*)(d + i) = lo;
        *(ushort4v*)(d + i + 4) = hi;
    }
}

// four conversions in one launch (in_w, out_w, xp_w, dt_w of a layer)
__global__ __launch_bounds__(256) void k_cvtL(const float* __restrict__ sa, u16* __restrict__ da, long long na,
                                              const float* __restrict__ sb, u16* __restrict__ db, long long nb,
                                              const float* __restrict__ sc, u16* __restrict__ dc, long long nc,
                                              const float* __restrict__ sd, u16* __restrict__ dd, long long nd) {
    const long long tot = na + nb + nc + nd;
    const long long stride = (long long)gridDim.x * 256 * 8;
    for (long long i = ((long long)blockIdx.x * 256 + threadIdx.x) * 8; i < tot; i += stride) {
        const float* s; u16* d; long long o = i;
        if (o < na) { s = sa; d = da; }
        else { o -= na;
            if (o < nb) { s = sb; d = db; }
            else { o -= nb;
                if (o < nc) { s = sc; d = dc; }
                else { o -= nc; s = sd; d = dd; } } }
        float4 a = *(const float4*)(s + o);
        float4 b = *(const float4*)(s + o + 4);
        *(ushort4v*)(d + o) = cvt4(a);
        *(ushort4v*)(d + o + 4) = cvt4(b);
    }
}

// ---------------- 128x128 bf16 GEMM, BK=32 ----------------
// C[M x N] = A[M x K] @ W[N x K]^T.  256 thr = 4 waves (2x2), wave-tile 64x64.
// NBUF=2: two-barrier loop, 32 KiB LDS -> 4 blocks/CU (head: 293-297us).
// NBUF=3: single-barrier loop, 48 KiB (grid-capped call sites, r7-best).
// Bank swizzle (verified 0-conflict r5): 16-B slot ^= (row>>1)&3.
// Epilogue: COOP=false -> per-wave transpose, 256-B contiguous stores (best
// for 128B-aligned ldc; r8 showed coop regresses these sites ~5us each).
// COOP=true -> block-coop transpose, 512-B contiguous rows (head, odd ldc).
// NTS: nontemporal stores (head C never re-read).
// EPI: 0 = none, 1 = softplus(v + bias[col]).
template<int MT, int EPI, bool NTS, int NBUF, bool COOP>   // grid = MT*(N/128), %8==0
__global__ __launch_bounds__(256, NBUF == 2 ? 4 : 3)
void k_gemm128(const u16* __restrict__ A,
               const u16* __restrict__ W,
               float* __restrict__ C,
               const float* __restrict__ bias,
               int N, int K, int ldc, int cpx) {
    __shared__ __align__(128) u16 lds[NBUF][8192];   // [buf][A 4096 | B 4096]
    const int tid = threadIdx.x;
    const int w = tid >> 6;
    const int lane = tid & 63;
    const int l16 = lane & 15;
    const int quad = lane >> 4;
    const int wm = (w >> 1) * 64;
    const int wn = (w & 1) * 64;
    // bijective XCD-aware block swizzle (nwg % 8 == 0 at all call sites)
    const int bid = blockIdx.x;
    const int orig = (bid & 7) * cpx + (bid >> 3);
    const int bm = orig & (MT - 1);
    const int bn = orig / MT;
    const int row0 = bm * 128, col0 = bn * 128;

    // staging: issue g = w*4+c covers rows g*16..g*16+15 (A for g<8, B else).
    const int scol = ((lane & 3) ^ ((lane >> 3) & 3)) * 8;   // u16 units
    const int lrow = lane >> 2;
    const u16* sbase[4];
#pragma unroll
    for (int c = 0; c < 4; ++c) {
        const int g = w * 4 + c;
        sbase[c] = (g < 8 ? A + (size_t)(row0 + g * 16 + lrow) * K
                          : W + (size_t)(col0 + (g - 8) * 16 + lrow) * K) + scol;
    }

    // swizzled ds_read col: fragment rows have (row>>1)&3 == (l16>>1)&3
    const int swz = (quad ^ ((l16 >> 1) & 3)) * 8;           // u16 units
    const int aoff = (wm + l16) * 32 + swz;                  // + ii*512
    const int boff = 4096 + (wn + l16) * 32 + swz;           // + j*512

    float4v acc[4][4];
#pragma unroll
    for (int i = 0; i < 4; ++i)
#pragma unroll
        for (int j = 0; j < 4; ++j)
#pragma unroll
            for (int r = 0; r < 4; ++r) acc[i][j][r] = 0.f;

    const int NT = K >> 5;
    u16* lds0 = &lds[0][0];

    auto stage_tile = [&](int buf, int t) {
        u16* dst = lds0 + buf * 8192;
#pragma unroll
        for (int c = 0; c < 4; ++c)
            gload_lds16(sbase[c] + t * 32, dst + (w * 4 + c) * 512);
    };

    // prologue: tiles 0,1 in flight; wait tile0 (own 4 of tile1 still out)
    stage_tile(0, 0);
    stage_tile(1, 1);
    asm volatile("s_waitcnt vmcnt(4)" ::: "memory");
    __builtin_amdgcn_s_barrier();

    if constexpr (NBUF == 2) {
        for (int n = 0; n < NT; ++n) {
            const u16* Ls = lds0 + (n & 1) * 8192;
            short8v af[4], bf[4];
#pragma unroll
            for (int ii = 0; ii < 4; ++ii)
                af[ii] = *(const short8v*)&Ls[aoff + ii * 512];
#pragma unroll
            for (int j = 0; j < 4; ++j)
                bf[j] = *(const short8v*)&Ls[boff + j * 512];
            __builtin_amdgcn_s_barrier();
            __builtin_amdgcn_s_setprio(1);
#pragma unroll
            for (int ii = 0; ii < 4; ++ii)
#pragma unroll
                for (int j = 0; j < 4; ++j)
                    acc[ii][j] = mfma_bf16(af[ii], bf[j], acc[ii][j]);
            __builtin_amdgcn_s_setprio(0);
            if (n + 2 < NT) {
                stage_tile(n & 1, n + 2);
                asm volatile("s_waitcnt vmcnt(4)" ::: "memory");   // tile n+1 landed
            } else if (n < NT - 1) {
                asm volatile("s_waitcnt vmcnt(0)" ::: "memory");
            }
            __builtin_amdgcn_s_barrier();
        }
    } else {
        int cur = 0;
        for (int n = 0; n < NT; ++n) {
            const u16* Ls = lds0 + cur * 8192;
            short8v af[4], bf[4];
#pragma unroll
            for (int ii = 0; ii < 4; ++ii)
                af[ii] = *(const short8v*)&Ls[aoff + ii * 512];
#pragma unroll
            for (int j = 0; j < 4; ++j)
                bf[j] = *(const short8v*)&Ls[boff + j * 512];
            const bool pf = (n + 2 < NT);
            if (pf) {
                int tg = cur + 2; if (tg >= 3) tg -= 3;
                stage_tile(tg, n + 2);      // readers of tg finished at iter n-1
            }
            __builtin_amdgcn_s_setprio(1);
#pragma unroll
            for (int ii = 0; ii < 4; ++ii)
#pragma unroll
                for (int j = 0; j < 4; ++j)
                    acc[ii][j] = mfma_bf16(af[ii], bf[j], acc[ii][j]);
            __builtin_amdgcn_s_setprio(0);
            if (pf)
                asm volatile("s_waitcnt vmcnt(4)" ::: "memory");
            else if (n + 1 < NT)
                asm volatile("s_waitcnt vmcnt(0)" ::: "memory");
            __builtin_amdgcn_s_barrier();
            ++cur; if (cur == 3) cur = 0;
        }
    }

    if constexpr (COOP) {
        // ---- block-coop transpose -> 512 B contiguous per output row ----
        float* lt = (float*)lds0;                 // 16 x 132 f32 (buffer 0)
        const int ecol = col0 + (tid & 127);
        const int rsel = tid >> 7;
        float bv = 0.f;
        if (EPI == 1 && ecol < N) bv = bias[ecol];
#pragma unroll
        for (int g = 0; g < 8; ++g) {             // rows g*16 .. g*16+15
            __syncthreads();
            if ((w >> 1) == (g >> 2)) {
                const int ii = g & 3;
#pragma unroll
                for (int j = 0; j < 4; ++j)
#pragma unroll
                    for (int r = 0; r < 4; ++r)
                        lt[(quad * 4 + r) * 132 + wn + j * 16 + l16] = acc[ii][j][r];
            }
            __syncthreads();
            if (ecol < N) {
                const int rbase = row0 + g * 16;
#pragma unroll
                for (int p = 0; p < 8; ++p) {
                    const int rr = p * 2 + rsel;
                    float v = lt[rr * 132 + (tid & 127)];
                    if (EPI == 1) { v += bv; v = (v > 20.f) ? v : log1pf(__expf(v)); }
                    float* pp = &C[(size_t)(rbase + rr) * ldc + ecol];
                    if (NTS) __builtin_nontemporal_store(v, pp);
                    else *pp = v;
                }
            }
        }
    } else {
        // ---- per-wave transpose -> 256 B contiguous stores ----
        float* lt = (float*)lds0 + (size_t)w * 1040;   // 16 x 65 f32 per wave
        const int ecol = col0 + wn + lane;
        float bv = 0.f;
        if (EPI == 1) bv = bias[(ecol < N) ? ecol : 0];
#pragma unroll
        for (int i = 0; i < 4; ++i) {
            __syncthreads();
#pragma unroll
            for (int j = 0; j < 4; ++j)
#pragma unroll
                for (int r = 0; r < 4; ++r)
                    lt[(quad * 4 + r) * 65 + j * 16 + l16] = acc[i][j][r];
            __syncthreads();
            if (ecol < N) {
                const int rbase = row0 + wm + i * 16;
#pragma unroll
                for (int t = 0; t < 16; ++t) {
                    float v = lt[t * 65 + lane];
                    if (EPI == 1) { v += bv; v = (v > 20.f) ? v : log1pf(__expf(v)); }
                    float* p = &C[(size_t)(rbase + t) * ldc + ecol];
                    if (NTS) __builtin_nontemporal_store(v, p);
                    else *p = v;
                }
            }
        }
    }
}

// ---------------- 64x64 bf16 GEMM, BK=64, 3-buffer single-barrier (out_proj) ----
template<int MT>   // grid = MT*(N/64), %8==0
__global__ __launch_bounds__(256, 3) void k_gemm64(const u16* __restrict__ A,
                                                   const u16* __restrict__ W,
                                                   float* __restrict__ C,
                                                   int N, int K, int ldc, int cpx) {
    __shared__ __align__(128) u16 lds[3][8192];
    const int tid = threadIdx.x;
    const int w = tid >> 6;
    const int lane = tid & 63;
    const int l16 = lane & 15;
    const int quad = lane >> 4;
    const int wm = (w >> 1) * 32;
    const int wn = (w & 1) * 32;
    const int bid = blockIdx.x;
    const int orig = (bid & 7) * cpx + (bid >> 3);
    const int bm = orig & (MT - 1);
    const int bn = orig / MT;
    const int row0 = bm * 64, col0 = bn * 64;

    const int scol = ((lane & 3) ^ ((lane >> 3) & 3)) * 8;   // u16 units
    const int lrow = lane >> 2;
    const u16* sbase[4];
#pragma unroll
    for (int c = 0; c < 4; ++c) {
        const int ch = w * 4 + c;
        const int isA = (ch < 8);
        const int cc = isA ? ch : (ch - 8);
        const int half = cc >> 2;
        const int rbase = (cc & 3) * 16;
        sbase[c] = (isA ? A + (size_t)(row0 + rbase + lrow) * K
                        : W + (size_t)(col0 + rbase + lrow) * K) + half * 32 + scol;
    }

    const int swz = (quad ^ ((l16 >> 1) & 3)) * 8;
    const int aoff = (wm + l16) * 32 + swz;
    const int boff = 4096 + (wn + l16) * 32 + swz;

    float4v acc[2][2];
#pragma unroll
    for (int i = 0; i < 2; ++i)
#pragma unroll
        for (int j = 0; j < 2; ++j)
#pragma unroll
            for (int r = 0; r < 4; ++r) acc[i][j][r] = 0.f;

    const int NT = K >> 6;
    u16* lds0 = &lds[0][0];

    auto stage_tile = [&](int buf, int t) {
        u16* dst = lds0 + buf * 8192;
#pragma unroll
        for (int c = 0; c < 4; ++c)
            gload_lds16(sbase[c] + t * 64, dst + (w * 4 + c) * 512);
    };

    stage_tile(0, 0);
    stage_tile(1, 1);
    asm volatile("s_waitcnt vmcnt(4)" ::: "memory");
    __builtin_amdgcn_s_barrier();

    int cur = 0;
    for (int n = 0; n < NT; ++n) {
        const u16* Ls = lds0 + cur * 8192;
        short8v af[2][2], bf[2][2];
#pragma unroll
        for (int ks = 0; ks < 2; ++ks) {
#pragma unroll
            for (int ii = 0; ii < 2; ++ii)
                af[ks][ii] = *(const short8v*)&Ls[ks * 2048 + aoff + ii * 512];
#pragma unroll
            for (int j = 0; j < 2; ++j)
                bf[ks][j] = *(const short8v*)&Ls[ks * 2048 + boff + j * 512];
        }
        const bool pf = (n + 2 < NT);
        if (pf) {
            int tg = cur + 2; if (tg >= 3) tg -= 3;
            stage_tile(tg, n + 2);
        }
        __builtin_amdgcn_s_setprio(1);
#pragma unroll
        for (int ks = 0; ks < 2; ++ks)
#pragma unroll
            for (int ii = 0; ii < 2; ++ii)
#pragma unroll
                for (int j = 0; j < 2; ++j)
                    acc[ii][j] = mfma_bf16(af[ks][ii], bf[ks][j], acc[ii][j]);
        __builtin_amdgcn_s_setprio(0);
        if (pf)
            asm volatile("s_waitcnt vmcnt(4)" ::: "memory");
        else if (n + 1 < NT)
            asm volatile("s_waitcnt vmcnt(0)" ::: "memory");
        __builtin_amdgcn_s_barrier();
        ++cur; if (cur == 3) cur = 0;
    }

    // ---- epilogue: transpose -> 2 rows x 128 B contiguous per instruction ----
    float* lt = (float*)lds0 + (size_t)w * 528;   // 16 x 33 f32 per wave
    const int c32 = lane & 31;
    const int rsub = lane >> 5;
    const int ecol = col0 + wn + c32;
#pragma unroll
    for (int i = 0; i < 2; ++i) {
        __syncthreads();
#pragma unroll
        for (int j = 0; j < 2; ++j)
#pragma unroll
            for (int r = 0; r < 4; ++r)
                lt[(quad * 4 + r) * 33 + j * 16 + l16] = acc[i][j][r];
        __syncthreads();
        if (ecol < N) {
            const int rbase = row0 + wm + i * 16;
#pragma unroll
            for (int t = 0; t < 8; ++t)
                C[(size_t)(rbase + 2 * t + rsub) * ldc + ecol] =
                    lt[(2 * t + rsub) * 33 + c32];
        }
    }
}

// ---------------- causal depthwise conv (K=4) + bias + silu -> fp32 + bf16 ----------------
__global__ __launch_bounds__(256) void k_conv(const float* __restrict__ xz,
                                              const float* __restrict__ cw,
                                              const float* __restrict__ cb,
                                              float* __restrict__ xc,
                                              u16* __restrict__ xc16) {
    const int e = blockIdx.x * 256 + threadIdx.x;
    const int t0 = blockIdx.y * 8;
    const float w0 = cw[e * 4 + 0], w1 = cw[e * 4 + 1], w2 = cw[e * 4 + 2], w3 = cw[e * 4 + 3];
    const float b = cb[e];
    float xm3 = (t0 >= 3) ? xz[(size_t)(t0 - 3) * (2 * EDIM) + e] : 0.f;
    float xm2 = (t0 >= 2) ? xz[(size_t)(t0 - 2) * (2 * EDIM) + e] : 0.f;
    float xm1 = (t0 >= 1) ? xz[(size_t)(t0 - 1) * (2 * EDIM) + e] : 0.f;
#pragma unroll
    for (int s = 0; s < 8; ++s) {
        const int t = t0 + s;
        const float xt = xz[(size_t)t * (2 * EDIM) + e];
        const float v = w0 * xm3 + w1 * xm2 + w2 * xm1 + w3 * xt + b;
        const float sv = v / (1.f + __expf(-v));
        xc[(size_t)t * EDIM + e] = sv;
        xc16[(size_t)t * EDIM + e] = f2bf(sv);
        xm3 = xm2; xm2 = xm1; xm1 = xt;
    }
}

// ---------------- skinny GEMM: dbc[L x 96] = xc16[L x E] @ xpW16[96 x E]^T ---------
__global__ __launch_bounds__(256) void k_xproj(const u16* __restrict__ xc,
                                               const u16* __restrict__ W,
                                               float* __restrict__ dbc,
                                               u16* __restrict__ dbc16) {
    const int tid = threadIdx.x;
    const int wave = tid >> 6, lane = tid & 63;
    const int l16 = lane & 15, quad = lane >> 4;
    const int m = blockIdx.x * 16 + l16;
    const int kb = wave * (EDIM / 4);
    float4v acc[6];
#pragma unroll
    for (int j = 0; j < 6; ++j)
#pragma unroll
        for (int r = 0; r < 4; ++r) acc[j][r] = 0.f;

    for (int ks = 0; ks < EDIM / 4; ks += 32) {
        const int k = kb + ks + quad * 8;
        const short8v af = *(const short8v*)(xc + (size_t)m * EDIM + k);
#pragma unroll
        for (int j = 0; j < 6; ++j) {
            const short8v bf = *(const short8v*)(W + (size_t)(j * 16 + l16) * EDIM + k);
            acc[j] = mfma_bf16(af, bf, acc[j]);
        }
    }
    __shared__ float red[4][16][96];
#pragma unroll
    for (int j = 0; j < 6; ++j)
#pragma unroll
        for (int r = 0; r < 4; ++r)
            red[wave][quad * 4 + r][j * 16 + l16] = acc[j][r];
    __syncthreads();
    for (int idx = tid; idx < 16 * 96; idx += 256) {
        const int r = idx / 96, c = idx % 96;
        const float s = red[0][r][c] + red[1][r][c] + red[2][r][c] + red[3][r][c];
        const int row = blockIdx.x * 16 + r;
        dbc[(size_t)row * 96 + c] = s;
        if (c < 64) dbc16[(size_t)row * 64 + c] = f2bf(s);
    }
}

// ---------------- selective scan, 3-phase chunked ----------------
__global__ __launch_bounds__(256) void k_scanA(const float* __restrict__ dt,
                                               const float* __restrict__ xc,
                                               const float* __restrict__ dbc,
                                               const float* __restrict__ Al,
                                               float* __restrict__ hpart,
                                               float* __restrict__ sdtb) {
    const int e = blockIdx.y * 256 + threadIdx.x;
    const int c = blockIdx.x;
    float a[NST];
#pragma unroll
    for (int n = 0; n < NST; ++n) a[n] = -__expf(Al[(size_t)e * NST + n]);
    bool fast = true;
#pragma unroll
    for (int n = 0; n < NST; ++n)
        fast = fast && (fabsf(a[n] + (float)(n + 1)) < 1e-3f * (float)(n + 1));
    __align__(16) float h[NST];
#pragma unroll
    for (int n = 0; n < NST; ++n) h[n] = 0.f;
    float sdt = 0.f;
    const int t0 = c * TCHUNK;
    if (fast) {
        for (int s = 0; s < TCHUNK; ++s) {
            const int t = t0 + s;
            const float d = dt[(size_t)t * EDIM + e];
            const float x = xc[(size_t)t * EDIM + e];
            __align__(16) float Bv[NST];
#pragma unroll
            for (int q = 0; q < 4; ++q)
                *(float4*)&Bv[q * 4] = *(const float4*)&dbc[(size_t)t * 96 + 64 + q * 4];
            const float u = d * x;
            sdt += d;
            const float d1 = __expf(-d);
            float pw = 1.f;
#pragma unroll
            for (int n = 0; n < NST; ++n) { pw *= d1; h[n] = fmaf(pw, h[n], u * Bv[n]); }
        }
    } else {
        for (int s = 0; s < TCHUNK; ++s) {
            const int t = t0 + s;
            const float d = dt[(size_t)t * EDIM + e];
            const float x = xc[(size_t)t * EDIM + e];
            __align__(16) float Bv[NST];
#pragma unroll
            for (int q = 0; q < 4; ++q)
                *(float4*)&Bv[q * 4] = *(const float4*)&dbc[(size_t)t * 96 + 64 + q * 4];
            const float u = d * x;
            sdt += d;
#pragma unroll
            for (int n = 0; n < NST; ++n) h[n] = fmaf(__expf(d * a[n]), h[n], u * Bv[n]);
        }
    }
#pragma unroll
    for (int n = 0; n < NST; n += 4)
        *(float4*)&hpart[((size_t)c * EDIM + e) * NST + n] = *(float4*)&h[n];
    sdtb[(size_t)c * EDIM + e] = sdt;
}

__global__ __launch_bounds__(256) void k_scanB(float* __restrict__ hio,
                                               const float* __restrict__ sdtb,
                                               const float* __restrict__ Al) {
    const int idx = blockIdx.x * 256 + threadIdx.x;   // e*16 + n
    const int e = idx >> 4;
    const float a = -__expf(Al[idx]);
    float carry = 0.f;
    for (int c = 0; c < NCHUNK; ++c) {
        const size_t off = ((size_t)c * EDIM + e) * NST + (idx & 15);
        const float hp = hio[off];
        const float ap = __expf(a * sdtb[(size_t)c * EDIM + e]);
        hio[off] = carry;
        carry = fmaf(ap, carry, hp);
    }
}

__global__ __launch_bounds__(256) void k_scanC(const float* __restrict__ dt,
                                               const float* __restrict__ xc,
                                               const float* __restrict__ dbc,
                                               const float* __restrict__ xz,
                                               const float* __restrict__ Al,
                                               const float* __restrict__ Dl,
                                               const float* __restrict__ hin,
                                               u16* __restrict__ y) {
    const int e = blockIdx.y * 256 + threadIdx.x;
    const int c = blockIdx.x;
    float a[NST];
#pragma unroll
    for (int n = 0; n < NST; ++n) a[n] = -__expf(Al[(size_t)e * NST + n]);
    bool fast = true;
#pragma unroll
    for (int n = 0; n < NST; ++n)
        fast = fast && (fabsf(a[n] + (float)(n + 1)) < 1e-3f * (float)(n + 1));
    __align__(16) float h[NST];
#pragma unroll
    for (int n = 0; n < NST; n += 4)
        *(float4*)&h[n] = *(const float4*)&hin[((size_t)c * EDIM + e) * NST + n];
    const float Dv = Dl[e];
    const int t0 = c * TCHUNK;
    for (int s = 0; s < TCHUNK; ++s) {
        const int t = t0 + s;
        const float d = dt[(size_t)t * EDIM + e];
        const float x = xc[(size_t)t * EDIM + e];
        __align__(16) float Bv[NST], Cv[NST];
#pragma unroll
        for (int q = 0; q < 4; ++q) {
            *(float4*)&Bv[q * 4] = *(const float4*)&dbc[(size_t)t * 96 + 64 + q * 4];
            *(float4*)&Cv[q * 4] = *(const float4*)&dbc[(size_t)t * 96 + 80 + q * 4];
        }
        const float u = d * x;
        float ys = 0.f;
        if (fast) {
            const float d1 = __expf(-d);
            float pw = 1.f;
#pragma unroll
            for (int n = 0; n < NST; ++n) {
                pw *= d1;
                h[n] = fmaf(pw, h[n], u * Bv[n]);
                ys = fmaf(h[n], Cv[n], ys);
            }
        } else {
#pragma unroll
            for (int n = 0; n < NST; ++n) {
                h[n] = fmaf(__expf(d * a[n]), h[n], u * Bv[n]);
                ys = fmaf(h[n], Cv[n], ys);
            }
        }
        const float z = xz[(size_t)t * (2 * EDIM) + EDIM + e];
        const float yv = ys + Dv * x;
        y[(size_t)t * EDIM + e] = f2bf(yv * (z / (1.f + __expf(-z))));
    }
}

extern "C" void kernel_launch(void* const* d_in, const int* in_sizes, int n_in,
                              void* d_out, int out_size, void* d_ws, size_t ws_size,
                              hipStream_t stream) {
    const int*   ids   = (const int*)d_in[0];
    const float* emb   = (const float*)d_in[1];
    const float* inW   = (const float*)d_in[2];
    const float* convW = (const float*)d_in[3];
    const float* convB = (const float*)d_in[4];
    const float* xpW   = (const float*)d_in[5];
    const float* dtW   = (const float*)d_in[6];
    const float* dtB   = (const float*)d_in[7];
    const float* Alog  = (const float*)d_in[8];
    const float* Dpar  = (const float*)d_in[9];
    const float* outW  = (const float*)d_in[10];
    const float* normW = (const float*)d_in[11];
    const float* normF = (const float*)d_in[12];
    const float* headW = (const float*)d_in[13];
    float* out = (float*)d_out;

    // ---- workspace layout (~210 MB, r7-identical) ----
    float* ws    = (float*)d_ws;
    float* res   = ws;                                      // L*D
    float* xzb   = res   + (size_t)LSEQ * DMODEL;           // L*2E
    float* xcb   = xzb   + (size_t)LSEQ * 2 * EDIM;         // L*E
    float* dbcb  = xcb   + (size_t)LSEQ * EDIM;             // L*96
    float* dtb   = dbcb  + (size_t)LSEQ * 96;               // L*E
    float* xob   = dtb   + (size_t)LSEQ * EDIM;             // L*D
    float* hpart = xob   + (size_t)LSEQ * DMODEL;           // NCHUNK*E*NST
    float* sdtb  = hpart + (size_t)NCHUNK * EDIM * NST;     // NCHUNK*E
    u16* hbf  = (u16*)(sdtb + (size_t)NCHUNK * EDIM);       // L*D   bf16
    u16* ybf  = hbf  + (size_t)LSEQ * DMODEL;               // L*E   bf16
    u16* wbf  = ybf  + (size_t)LSEQ * EDIM;                 // NPADV*D bf16 scratch (head)
    u16* wbf2 = wbf  + (size_t)2 * EDIM * DMODEL;           // out_w slot
    // layer-lifetime buffers carved from the unused tail of the head scratch:
    u16* xc16  = wbf  + (size_t)12 * 1024 * 1024;           // L*E bf16
    u16* dbc16 = xc16 + (size_t)LSEQ * EDIM;                // L*64 bf16
    u16* xpw16 = dbc16 + (size_t)LSEQ * DTRANK;             // 96*E bf16
    u16* dtw16 = xpw16 + (size_t)96 * EDIM;                 // E*64 bf16

    k_embed<<<LSEQ, 256, 0, stream>>>(ids, emb, res);

    for (int i = 0; i < NLAYER; ++i) {
        if (i == 0)
            k_addnorm<false><<<LSEQ, 256, 0, stream>>>(res, nullptr, normW, hbf);
        else
            k_addnorm<true><<<LSEQ, 256, 0, stream>>>(res, xob, normW + (size_t)i * DMODEL, hbf);

        // convert this layer's weights to bf16 (in_w, out_w, xp_w, dt_w)
        k_cvtL<<<4096, 256, 0, stream>>>(
            inW  + (size_t)i * 2 * EDIM * DMODEL, wbf,   (long long)2 * EDIM * DMODEL,
            outW + (size_t)i * DMODEL * EDIM,     wbf2,  (long long)DMODEL * EDIM,
            xpW  + (size_t)i * 96 * EDIM,         xpw16, (long long)96 * EDIM,
            dtW  + (size_t)i * EDIM * DTRANK,     dtw16, (long long)EDIM * DTRANK);

        // xz = h @ in_w^T : (2048 x 4096), K=1024 — NBUF=3, per-wave epilogue
        k_gemm128<16, 0, false, 3, false><<<dim3(512), 256, 0, stream>>>(hbf, wbf, xzb,
                nullptr, 2 * EDIM, DMODEL, 2 * EDIM, 64);

        k_conv<<<dim3(8, 256), 256, 0, stream>>>(xzb, convW + (size_t)i * EDIM * 4,
                convB + (size_t)i * EDIM, xcb, xc16);

        // dbc = xc @ xp_w^T : (2048 x 96), K=2048  (bf16 in, fp32 + bf16 out)
        k_xproj<<<128, 256, 0, stream>>>(xc16, xpw16, dbcb, dbc16);

        // dt = softplus(dbc16 @ dt_w^T + dt_b) : (2048 x 2048), K=64
        k_gemm128<16, 1, false, 3, false><<<dim3(256), 256, 0, stream>>>(dbc16, dtw16, dtb,
                dtB + (size_t)i * EDIM, EDIM, DTRANK, EDIM, 32);

        const float* Al = Alog + (size_t)i * EDIM * NST;
        k_scanA<<<dim3(NCHUNK, EDIM / 256), 256, 0, stream>>>(dtb, xcb, dbcb, Al, hpart, sdtb);
        k_scanB<<<(EDIM * NST) / 256, 256, 0, stream>>>(hpart, sdtb, Al);
        k_scanC<<<dim3(NCHUNK, EDIM / 256), 256, 0, stream>>>(dtb, xcb, dbcb, xzb, Al,
                Dpar + (size_t)i * EDIM, hpart, ybf);

        // x = y @ out_w^T : (2048 x 1024), K=2048 — pipelined 64² tile, grid 512
        k_gemm64<32><<<dim3(512), 256, 0, stream>>>(ybf, wbf2, xob,
                DMODEL, EDIM, DMODEL, 64);
    }

    k_addnorm<true><<<LSEQ, 256, 0, stream>>>(res, xob, normF, hbf);

    // head: convert W (padded to 50304 rows, zeros), then 128² GEMM
    // grid = 16*393 = 6288 (%8==0), ~24/CU -> NBUF=2 (4 blocks/CU), coop+NT stores
    k_cvt<<<4096, 256, 0, stream>>>(headW, wbf,
            (long long)NVOCAB * DMODEL, (long long)NPADV * DMODEL);
    k_gemm128<16, 0, true, 2, true><<<dim3(6288), 256, 0, stream>>>(hbf, wbf, out, nullptr,
            NVOCAB, DMODEL, NVOCAB, 6288 / 8);
}

// Round 11
// 2809.095 us; speedup vs baseline: 1.1029x; 1.1029x over previous
//
#include <hip/hip_runtime.h>
#include <math.h>

#define LSEQ 2048
#define DMODEL 1024
#define NLAYER 12
#define NVOCAB 50257
#define NPADV 50304          /* 393 * 128 */
#define EDIM 2048
#define NST 16
#define DTRANK 64
#define EPSV 1e-5f
#define NCHUNK 64
#define TCHUNK 32   /* LSEQ / NCHUNK */

typedef __attribute__((ext_vector_type(4))) float float4v;
typedef __attribute__((ext_vector_type(8))) short short8v;
typedef __attribute__((ext_vector_type(4))) unsigned short ushort4v;
typedef unsigned short u16;

__device__ __forceinline__ u16 f2bf(float f) {
    union { float f; unsigned int u; } v; v.f = f;
    unsigned int r = v.u + 0x7FFFu + ((v.u >> 16) & 1u);   // RNE
    return (u16)(r >> 16);
}

__device__ __forceinline__ ushort4v cvt4(float4 a) {
    ushort4v r; r[0] = f2bf(a.x); r[1] = f2bf(a.y); r[2] = f2bf(a.z); r[3] = f2bf(a.w);
    return r;
}

__device__ __forceinline__ float4v mfma_bf16(short8v a, short8v b, float4v c) {
    return __builtin_amdgcn_mfma_f32_16x16x32_bf16(a, b, c, 0, 0, 0);
}

// async global->LDS, 16 B per lane; LDS dest = wave-uniform base + lane*16
__device__ __forceinline__ void gload_lds16(const void* g, void* l) {
    __builtin_amdgcn_global_load_lds(
        (const __attribute__((address_space(1))) unsigned int*)g,
        (__attribute__((address_space(3))) unsigned int*)l,
        16, 0, 0);
}

// ---------------- embedding gather ----------------
__global__ __launch_bounds__(256) void k_embed(const int* __restrict__ ids,
                                               const float* __restrict__ emb,
                                               float* __restrict__ res) {
    const int t = blockIdx.x;
    const int row = ids[t];
    ((float4*)(res + (size_t)t * DMODEL))[threadIdx.x] =
        ((const float4*)(emb + (size_t)row * DMODEL))[threadIdx.x];
}

// ---------------- residual add + rmsnorm -> bf16 h ----------------
template<bool ADD>
__global__ __launch_bounds__(256) void k_addnorm(float* __restrict__ res,
                                                 const float* __restrict__ xin,
                                                 const float* __restrict__ w,
                                                 u16* __restrict__ h) {
    const int t = blockIdx.x;
    const int i = threadIdx.x;
    float4 r = ((float4*)(res + (size_t)t * DMODEL))[i];
    if (ADD) {
        float4 xv = ((const float4*)(xin + (size_t)t * DMODEL))[i];
        r.x += xv.x; r.y += xv.y; r.z += xv.z; r.w += xv.w;
        ((float4*)(res + (size_t)t * DMODEL))[i] = r;
    }
    float ss = r.x * r.x + r.y * r.y + r.z * r.z + r.w * r.w;
#pragma unroll
    for (int off = 32; off > 0; off >>= 1) ss += __shfl_xor(ss, off);
    __shared__ float part[4];
    if ((i & 63) == 0) part[i >> 6] = ss;
    __syncthreads();
    float tot = part[0] + part[1] + part[2] + part[3];
    const float inv = rsqrtf(tot * (1.f / DMODEL) + EPSV);
    float4 wv = ((const float4*)w)[i];
    float4 o;
    o.x = r.x * inv * wv.x; o.y = r.y * inv * wv.y;
    o.z = r.z * inv * wv.z; o.w = r.w * inv * wv.w;
    ((ushort4v*)(h + (size_t)t * DMODEL))[i] = cvt4(o);
}

// ---------------- fp32 -> bf16 weight conversion (with zero pad) ----------------
__global__ __launch_bounds__(256) void k_cvt(const float* __restrict__ s, u16* __restrict__ d,
                                             long long n, long long ntot) {
    const long long stride = (long long)gridDim.x * 256 * 8;
    for (long long i = ((long long)blockIdx.x * 256 + threadIdx.x) * 8; i < ntot; i += stride) {
        ushort4v lo, hi;
        if (i < n) {   // n is a multiple of 8, no straddle
            float4 a = *(const float4*)(s + i);
            float4 b = *(const float4*)(s + i + 4);
            lo = cvt4(a); hi = cvt4(b);
        } else {
            lo[0] = lo[1] = lo[2] = lo[3] = 0;
            hi[0] = hi[1] = hi[2] = hi[3] = 0;
        }
        *(ushort4v*)(d + i) = lo;
        *(ushort4v*)(d + i + 4) = hi;
    }
}

// four conversions in one launch (in_w, out_w, xp_w, dt_w of a layer)
__global__ __launch_bounds__(256) void k_cvtL(const float* __restrict__ sa, u16* __restrict__ da, long long na,
                                              const float* __restrict__ sb, u16* __restrict__ db, long long nb,
                                              const float* __restrict__ sc, u16* __restrict__ dc, long long nc,
                                              const float* __restrict__ sd, u16* __restrict__ dd, long long nd) {
    const long long tot = na + nb + nc + nd;
    const long long stride = (long long)gridDim.x * 256 * 8;
    for (long long i = ((long long)blockIdx.x * 256 + threadIdx.x) * 8; i < tot; i += stride) {
        const float* s; u16* d; long long o = i;
        if (o < na) { s = sa; d = da; }
        else { o -= na;
            if (o < nb) { s = sb; d = db; }
            else { o -= nb;
                if (o < nc) { s = sc; d = dc; }
                else { o -= nc; s = sd; d = dd; } } }
        float4 a = *(const float4*)(s + o);
        float4 b = *(const float4*)(s + o + 4);
        *(ushort4v*)(d + o) = cvt4(a);
        *(ushort4v*)(d + o + 4) = cvt4(b);
    }
}

// ---------------- 128x128 bf16 GEMM, BK=32 ----------------
// C[M x N] = A[M x K] @ W[N x K]^T.  256 thr = 4 waves (2x2), wave-tile 64x64.
// NBUF=2: two-barrier loop, 32 KiB LDS -> 4 blocks/CU (head: 293-297us).
//   r11 hardening: the mid barrier now drains lgkmcnt(0) first — the later
//   stage_tile re-stages the just-read buffer, and other waves' ds_reads of it
//   were only guaranteed ISSUED (not complete) at a raw s_barrier.
// NBUF=3: single-barrier loop, 48 KiB (grid-capped call sites; sound as-is:
//   reads are consumed by MFMA before the barrier the stage follows).
// Bank swizzle (verified 0-conflict r5): 16-B slot ^= (row>>1)&3.
// Epilogue: COOP=false -> per-wave transpose, 256-B contiguous stores.
// COOP=true -> block-coop transpose, 512-B contiguous rows (head, odd ldc).
// NTS: nontemporal stores (head C never re-read).
// EPI: 0 = none, 1 = softplus(v + bias[col]).
template<int MT, int EPI, bool NTS, int NBUF, bool COOP>   // grid = MT*(N/128), %8==0
__global__ __launch_bounds__(256, NBUF == 2 ? 4 : 3)
void k_gemm128(const u16* __restrict__ A,
               const u16* __restrict__ W,
               float* __restrict__ C,
               const float* __restrict__ bias,
               int N, int K, int ldc, int cpx) {
    __shared__ __align__(128) u16 lds[NBUF][8192];   // [buf][A 4096 | B 4096]
    const int tid = threadIdx.x;
    const int w = tid >> 6;
    const int lane = tid & 63;
    const int l16 = lane & 15;
    const int quad = lane >> 4;
    const int wm = (w >> 1) * 64;
    const int wn = (w & 1) * 64;
    // bijective XCD-aware block swizzle (nwg % 8 == 0 at all call sites)
    const int bid = blockIdx.x;
    const int orig = (bid & 7) * cpx + (bid >> 3);
    const int bm = orig & (MT - 1);
    const int bn = orig / MT;
    const int row0 = bm * 128, col0 = bn * 128;

    // staging: issue g = w*4+c covers rows g*16..g*16+15 (A for g<8, B else).
    const int scol = ((lane & 3) ^ ((lane >> 3) & 3)) * 8;   // u16 units
    const int lrow = lane >> 2;
    const u16* sbase[4];
#pragma unroll
    for (int c = 0; c < 4; ++c) {
        const int g = w * 4 + c;
        sbase[c] = (g < 8 ? A + (size_t)(row0 + g * 16 + lrow) * K
                          : W + (size_t)(col0 + (g - 8) * 16 + lrow) * K) + scol;
    }

    // swizzled ds_read col: fragment rows have (row>>1)&3 == (l16>>1)&3
    const int swz = (quad ^ ((l16 >> 1) & 3)) * 8;           // u16 units
    const int aoff = (wm + l16) * 32 + swz;                  // + ii*512
    const int boff = 4096 + (wn + l16) * 32 + swz;           // + j*512

    float4v acc[4][4];
#pragma unroll
    for (int i = 0; i < 4; ++i)
#pragma unroll
        for (int j = 0; j < 4; ++j)
#pragma unroll
            for (int r = 0; r < 4; ++r) acc[i][j][r] = 0.f;

    const int NT = K >> 5;
    u16* lds0 = &lds[0][0];

    auto stage_tile = [&](int buf, int t) {
        u16* dst = lds0 + buf * 8192;
#pragma unroll
        for (int c = 0; c < 4; ++c)
            gload_lds16(sbase[c] + t * 32, dst + (w * 4 + c) * 512);
    };

    // prologue: tiles 0,1 in flight; wait tile0 (own 4 of tile1 still out)
    stage_tile(0, 0);
    stage_tile(1, 1);
    asm volatile("s_waitcnt vmcnt(4)" ::: "memory");
    __builtin_amdgcn_s_barrier();

    if constexpr (NBUF == 2) {
        for (int n = 0; n < NT; ++n) {
            const u16* Ls = lds0 + (n & 1) * 8192;
            short8v af[4], bf[4];
#pragma unroll
            for (int ii = 0; ii < 4; ++ii)
                af[ii] = *(const short8v*)&Ls[aoff + ii * 512];
#pragma unroll
            for (int j = 0; j < 4; ++j)
                bf[j] = *(const short8v*)&Ls[boff + j * 512];
            // drain ds_reads so every wave's reads of this buffer have COMPLETED
            // before any wave crosses and later re-stages it (r11 hardening)
            asm volatile("s_waitcnt lgkmcnt(0)" ::: "memory");
            __builtin_amdgcn_s_barrier();
            __builtin_amdgcn_s_setprio(1);
#pragma unroll
            for (int ii = 0; ii < 4; ++ii)
#pragma unroll
                for (int j = 0; j < 4; ++j)
                    acc[ii][j] = mfma_bf16(af[ii], bf[j], acc[ii][j]);
            __builtin_amdgcn_s_setprio(0);
            if (n + 2 < NT) {
                stage_tile(n & 1, n + 2);
                asm volatile("s_waitcnt vmcnt(4)" ::: "memory");   // tile n+1 landed
            } else if (n < NT - 1) {
                asm volatile("s_waitcnt vmcnt(0)" ::: "memory");
            }
            __builtin_amdgcn_s_barrier();
        }
    } else {
        int cur = 0;
        for (int n = 0; n < NT; ++n) {
            const u16* Ls = lds0 + cur * 8192;
            short8v af[4], bf[4];
#pragma unroll
            for (int ii = 0; ii < 4; ++ii)
                af[ii] = *(const short8v*)&Ls[aoff + ii * 512];
#pragma unroll
            for (int j = 0; j < 4; ++j)
                bf[j] = *(const short8v*)&Ls[boff + j * 512];
            const bool pf = (n + 2 < NT);
            if (pf) {
                int tg = cur + 2; if (tg >= 3) tg -= 3;
                stage_tile(tg, n + 2);      // readers of tg finished at iter n-1
            }
            __builtin_amdgcn_s_setprio(1);
#pragma unroll
            for (int ii = 0; ii < 4; ++ii)
#pragma unroll
                for (int j = 0; j < 4; ++j)
                    acc[ii][j] = mfma_bf16(af[ii], bf[j], acc[ii][j]);
            __builtin_amdgcn_s_setprio(0);
            if (pf)
                asm volatile("s_waitcnt vmcnt(4)" ::: "memory");
            else if (n + 1 < NT)
                asm volatile("s_waitcnt vmcnt(0)" ::: "memory");
            __builtin_amdgcn_s_barrier();
            ++cur; if (cur == 3) cur = 0;
        }
    }

    if constexpr (COOP) {
        // ---- block-coop transpose -> 512 B contiguous per output row ----
        float* lt = (float*)lds0;                 // 16 x 132 f32 (buffer 0)
        const int ecol = col0 + (tid & 127);
        const int rsel = tid >> 7;
        float bv = 0.f;
        if (EPI == 1 && ecol < N) bv = bias[ecol];
#pragma unroll
        for (int g = 0; g < 8; ++g) {             // rows g*16 .. g*16+15
            __syncthreads();
            if ((w >> 1) == (g >> 2)) {
                const int ii = g & 3;
#pragma unroll
                for (int j = 0; j < 4; ++j)
#pragma unroll
                    for (int r = 0; r < 4; ++r)
                        lt[(quad * 4 + r) * 132 + wn + j * 16 + l16] = acc[ii][j][r];
            }
            __syncthreads();
            if (ecol < N) {
                const int rbase = row0 + g * 16;
#pragma unroll
                for (int p = 0; p < 8; ++p) {
                    const int rr = p * 2 + rsel;
                    float v = lt[rr * 132 + (tid & 127)];
                    if (EPI == 1) { v += bv; v = (v > 20.f) ? v : log1pf(__expf(v)); }
                    float* pp = &C[(size_t)(rbase + rr) * ldc + ecol];
                    if (NTS) __builtin_nontemporal_store(v, pp);
                    else *pp = v;
                }
            }
        }
    } else {
        // ---- per-wave transpose -> 256 B contiguous stores ----
        float* lt = (float*)lds0 + (size_t)w * 1040;   // 16 x 65 f32 per wave
        const int ecol = col0 + wn + lane;
        float bv = 0.f;
        if (EPI == 1) bv = bias[(ecol < N) ? ecol : 0];
#pragma unroll
        for (int i = 0; i < 4; ++i) {
            __syncthreads();
#pragma unroll
            for (int j = 0; j < 4; ++j)
#pragma unroll
                for (int r = 0; r < 4; ++r)
                    lt[(quad * 4 + r) * 65 + j * 16 + l16] = acc[i][j][r];
            __syncthreads();
            if (ecol < N) {
                const int rbase = row0 + wm + i * 16;
#pragma unroll
                for (int t = 0; t < 16; ++t) {
                    float v = lt[t * 65 + lane];
                    if (EPI == 1) { v += bv; v = (v > 20.f) ? v : log1pf(__expf(v)); }
                    float* p = &C[(size_t)(rbase + t) * ldc + ecol];
                    if (NTS) __builtin_nontemporal_store(v, p);
                    else *p = v;
                }
            }
        }
    }
}

// ---------------- 64x64 bf16 GEMM, BK=64, 3-buffer single-barrier (out_proj) ----
template<int MT>   // grid = MT*(N/64), %8==0
__global__ __launch_bounds__(256, 3) void k_gemm64(const u16* __restrict__ A,
                                                   const u16* __restrict__ W,
                                                   float* __restrict__ C,
                                                   int N, int K, int ldc, int cpx) {
    __shared__ __align__(128) u16 lds[3][8192];
    const int tid = threadIdx.x;
    const int w = tid >> 6;
    const int lane = tid & 63;
    const int l16 = lane & 15;
    const int quad = lane >> 4;
    const int wm = (w >> 1) * 32;
    const int wn = (w & 1) * 32;
    const int bid = blockIdx.x;
    const int orig = (bid & 7) * cpx + (bid >> 3);
    const int bm = orig & (MT - 1);
    const int bn = orig / MT;
    const int row0 = bm * 64, col0 = bn * 64;

    const int scol = ((lane & 3) ^ ((lane >> 3) & 3)) * 8;   // u16 units
    const int lrow = lane >> 2;
    const u16* sbase[4];
#pragma unroll
    for (int c = 0; c < 4; ++c) {
        const int ch = w * 4 + c;
        const int isA = (ch < 8);
        const int cc = isA ? ch : (ch - 8);
        const int half = cc >> 2;
        const int rbase = (cc & 3) * 16;
        sbase[c] = (isA ? A + (size_t)(row0 + rbase + lrow) * K
                        : W + (size_t)(col0 + rbase + lrow) * K) + half * 32 + scol;
    }

    const int swz = (quad ^ ((l16 >> 1) & 3)) * 8;
    const int aoff = (wm + l16) * 32 + swz;
    const int boff = 4096 + (wn + l16) * 32 + swz;

    float4v acc[2][2];
#pragma unroll
    for (int i = 0; i < 2; ++i)
#pragma unroll
        for (int j = 0; j < 2; ++j)
#pragma unroll
            for (int r = 0; r < 4; ++r) acc[i][j][r] = 0.f;

    const int NT = K >> 6;
    u16* lds0 = &lds[0][0];

    auto stage_tile = [&](int buf, int t) {
        u16* dst = lds0 + buf * 8192;
#pragma unroll
        for (int c = 0; c < 4; ++c)
            gload_lds16(sbase[c] + t * 64, dst + (w * 4 + c) * 512);
    };

    stage_tile(0, 0);
    stage_tile(1, 1);
    asm volatile("s_waitcnt vmcnt(4)" ::: "memory");
    __builtin_amdgcn_s_barrier();

    int cur = 0;
    for (int n = 0; n < NT; ++n) {
        const u16* Ls = lds0 + cur * 8192;
        short8v af[2][2], bf[2][2];
#pragma unroll
        for (int ks = 0; ks < 2; ++ks) {
#pragma unroll
            for (int ii = 0; ii < 2; ++ii)
                af[ks][ii] = *(const short8v*)&Ls[ks * 2048 + aoff + ii * 512];
#pragma unroll
            for (int j = 0; j < 2; ++j)
                bf[ks][j] = *(const short8v*)&Ls[ks * 2048 + boff + j * 512];
        }
        const bool pf = (n + 2 < NT);
        if (pf) {
            int tg = cur + 2; if (tg >= 3) tg -= 3;
            stage_tile(tg, n + 2);
        }
        __builtin_amdgcn_s_setprio(1);
#pragma unroll
        for (int ks = 0; ks < 2; ++ks)
#pragma unroll
            for (int ii = 0; ii < 2; ++ii)
#pragma unroll
                for (int j = 0; j < 2; ++j)
                    acc[ii][j] = mfma_bf16(af[ks][ii], bf[ks][j], acc[ii][j]);
        __builtin_amdgcn_s_setprio(0);
        if (pf)
            asm volatile("s_waitcnt vmcnt(4)" ::: "memory");
        else if (n + 1 < NT)
            asm volatile("s_waitcnt vmcnt(0)" ::: "memory");
        __builtin_amdgcn_s_barrier();
        ++cur; if (cur == 3) cur = 0;
    }

    // ---- epilogue: transpose -> 2 rows x 128 B contiguous per instruction ----
    float* lt = (float*)lds0 + (size_t)w * 528;   // 16 x 33 f32 per wave
    const int c32 = lane & 31;
    const int rsub = lane >> 5;
    const int ecol = col0 + wn + c32;
#pragma unroll
    for (int i = 0; i < 2; ++i) {
        __syncthreads();
#pragma unroll
        for (int j = 0; j < 2; ++j)
#pragma unroll
            for (int r = 0; r < 4; ++r)
                lt[(quad * 4 + r) * 33 + j * 16 + l16] = acc[i][j][r];
        __syncthreads();
        if (ecol < N) {
            const int rbase = row0 + wm + i * 16;
#pragma unroll
            for (int t = 0; t < 8; ++t)
                C[(size_t)(rbase + 2 * t + rsub) * ldc + ecol] =
                    lt[(2 * t + rsub) * 33 + c32];
        }
    }
}

// ---------------- causal depthwise conv (K=4) + bias + silu -> fp32 + bf16 ----------------
__global__ __launch_bounds__(256) void k_conv(const float* __restrict__ xz,
                                              const float* __restrict__ cw,
                                              const float* __restrict__ cb,
                                              float* __restrict__ xc,
                                              u16* __restrict__ xc16) {
    const int e = blockIdx.x * 256 + threadIdx.x;
    const int t0 = blockIdx.y * 8;
    const float w0 = cw[e * 4 + 0], w1 = cw[e * 4 + 1], w2 = cw[e * 4 + 2], w3 = cw[e * 4 + 3];
    const float b = cb[e];
    float xm3 = (t0 >= 3) ? xz[(size_t)(t0 - 3) * (2 * EDIM) + e] : 0.f;
    float xm2 = (t0 >= 2) ? xz[(size_t)(t0 - 2) * (2 * EDIM) + e] : 0.f;
    float xm1 = (t0 >= 1) ? xz[(size_t)(t0 - 1) * (2 * EDIM) + e] : 0.f;
#pragma unroll
    for (int s = 0; s < 8; ++s) {
        const int t = t0 + s;
        const float xt = xz[(size_t)t * (2 * EDIM) + e];
        const float v = w0 * xm3 + w1 * xm2 + w2 * xm1 + w3 * xt + b;
        const float sv = v / (1.f + __expf(-v));
        xc[(size_t)t * EDIM + e] = sv;
        xc16[(size_t)t * EDIM + e] = f2bf(sv);
        xm3 = xm2; xm2 = xm1; xm1 = xt;
    }
}

// ---------------- skinny GEMM: dbc[L x 96] = xc16[L x E] @ xpW16[96 x E]^T ---------
__global__ __launch_bounds__(256) void k_xproj(const u16* __restrict__ xc,
                                               const u16* __restrict__ W,
                                               float* __restrict__ dbc,
                                               u16* __restrict__ dbc16) {
    const int tid = threadIdx.x;
    const int wave = tid >> 6, lane = tid & 63;
    const int l16 = lane & 15, quad = lane >> 4;
    const int m = blockIdx.x * 16 + l16;
    const int kb = wave * (EDIM / 4);
    float4v acc[6];
#pragma unroll
    for (int j = 0; j < 6; ++j)
#pragma unroll
        for (int r = 0; r < 4; ++r) acc[j][r] = 0.f;

    for (int ks = 0; ks < EDIM / 4; ks += 32) {
        const int k = kb + ks + quad * 8;
        const short8v af = *(const short8v*)(xc + (size_t)m * EDIM + k);
#pragma unroll
        for (int j = 0; j < 6; ++j) {
            const short8v bf = *(const short8v*)(W + (size_t)(j * 16 + l16) * EDIM + k);
            acc[j] = mfma_bf16(af, bf, acc[j]);
        }
    }
    __shared__ float red[4][16][96];
#pragma unroll
    for (int j = 0; j < 6; ++j)
#pragma unroll
        for (int r = 0; r < 4; ++r)
            red[wave][quad * 4 + r][j * 16 + l16] = acc[j][r];
    __syncthreads();
    for (int idx = tid; idx < 16 * 96; idx += 256) {
        const int r = idx / 96, c = idx % 96;
        const float s = red[0][r][c] + red[1][r][c] + red[2][r][c] + red[3][r][c];
        const int row = blockIdx.x * 16 + r;
        dbc[(size_t)row * 96 + c] = s;
        if (c < 64) dbc16[(size_t)row * 64 + c] = f2bf(s);
    }
}

// ---------------- selective scan, 3-phase chunked ----------------
__global__ __launch_bounds__(256) void k_scanA(const float* __restrict__ dt,
                                               const float* __restrict__ xc,
                                               const float* __restrict__ dbc,
                                               const float* __restrict__ Al,
                                               float* __restrict__ hpart,
                                               float* __restrict__ sdtb) {
    const int e = blockIdx.y * 256 + threadIdx.x;
    const int c = blockIdx.x;
    float a[NST];
#pragma unroll
    for (int n = 0; n < NST; ++n) a[n] = -__expf(Al[(size_t)e * NST + n]);
    bool fast = true;
#pragma unroll
    for (int n = 0; n < NST; ++n)
        fast = fast && (fabsf(a[n] + (float)(n + 1)) < 1e-3f * (float)(n + 1));
    __align__(16) float h[NST];
#pragma unroll
    for (int n = 0; n < NST; ++n) h[n] = 0.f;
    float sdt = 0.f;
    const int t0 = c * TCHUNK;
    if (fast) {
        for (int s = 0; s < TCHUNK; ++s) {
            const int t = t0 + s;
            const float d = dt[(size_t)t * EDIM + e];
            const float x = xc[(size_t)t * EDIM + e];
            __align__(16) float Bv[NST];
#pragma unroll
            for (int q = 0; q < 4; ++q)
                *(float4*)&Bv[q * 4] = *(const float4*)&dbc[(size_t)t * 96 + 64 + q * 4];
            const float u = d * x;
            sdt += d;
            const float d1 = __expf(-d);
            float pw = 1.f;
#pragma unroll
            for (int n = 0; n < NST; ++n) { pw *= d1; h[n] = fmaf(pw, h[n], u * Bv[n]); }
        }
    } else {
        for (int s = 0; s < TCHUNK; ++s) {
            const int t = t0 + s;
            const float d = dt[(size_t)t * EDIM + e];
            const float x = xc[(size_t)t * EDIM + e];
            __align__(16) float Bv[NST];
#pragma unroll
            for (int q = 0; q < 4; ++q)
                *(float4*)&Bv[q * 4] = *(const float4*)&dbc[(size_t)t * 96 + 64 + q * 4];
            const float u = d * x;
            sdt += d;
#pragma unroll
            for (int n = 0; n < NST; ++n) h[n] = fmaf(__expf(d * a[n]), h[n], u * Bv[n]);
        }
    }
#pragma unroll
    for (int n = 0; n < NST; n += 4)
        *(float4*)&hpart[((size_t)c * EDIM + e) * NST + n] = *(float4*)&h[n];
    sdtb[(size_t)c * EDIM + e] = sdt;
}

__global__ __launch_bounds__(256) void k_scanB(float* __restrict__ hio,
                                               const float* __restrict__ sdtb,
                                               const float* __restrict__ Al) {
    const int idx = blockIdx.x * 256 + threadIdx.x;   // e*16 + n
    const int e = idx >> 4;
    const float a = -__expf(Al[idx]);
    float carry = 0.f;
    for (int c = 0; c < NCHUNK; ++c) {
        const size_t off = ((size_t)c * EDIM + e) * NST + (idx & 15);
        const float hp = hio[off];
        const float ap = __expf(a * sdtb[(size_t)c * EDIM + e]);
        hio[off] = carry;
        carry = fmaf(ap, carry, hp);
    }
}

__global__ __launch_bounds__(256) void k_scanC(const float* __restrict__ dt,
                                               const float* __restrict__ xc,
                                               const float* __restrict__ dbc,
                                               const float* __restrict__ xz,
                                               const float* __restrict__ Al,
                                               const float* __restrict__ Dl,
                                               const float* __restrict__ hin,
                                               u16* __restrict__ y) {
    const int e = blockIdx.y * 256 + threadIdx.x;
    const int c = blockIdx.x;
    float a[NST];
#pragma unroll
    for (int n = 0; n < NST; ++n) a[n] = -__expf(Al[(size_t)e * NST + n]);
    bool fast = true;
#pragma unroll
    for (int n = 0; n < NST; ++n)
        fast = fast && (fabsf(a[n] + (float)(n + 1)) < 1e-3f * (float)(n + 1));
    __align__(16) float h[NST];
#pragma unroll
    for (int n = 0; n < NST; n += 4)
        *(float4*)&h[n] = *(const float4*)&hin[((size_t)c * EDIM + e) * NST + n];
    const float Dv = Dl[e];
    const int t0 = c * TCHUNK;
    for (int s = 0; s < TCHUNK; ++s) {
        const int t = t0 + s;
        const float d = dt[(size_t)t * EDIM + e];
        const float x = xc[(size_t)t * EDIM + e];
        __align__(16) float Bv[NST], Cv[NST];
#pragma unroll
        for (int q = 0; q < 4; ++q) {
            *(float4*)&Bv[q * 4] = *(const float4*)&dbc[(size_t)t * 96 + 64 + q * 4];
            *(float4*)&Cv[q * 4] = *(const float4*)&dbc[(size_t)t * 96 + 80 + q * 4];
        }
        const float u = d * x;
        float ys = 0.f;
        if (fast) {
            const float d1 = __expf(-d);
            float pw = 1.f;
#pragma unroll
            for (int n = 0; n < NST; ++n) {
                pw *= d1;
                h[n] = fmaf(pw, h[n], u * Bv[n]);
                ys = fmaf(h[n], Cv[n], ys);
            }
        } else {
#pragma unroll
            for (int n = 0; n < NST; ++n) {
                h[n] = fmaf(__expf(d * a[n]), h[n], u * Bv[n]);
                ys = fmaf(h[n], Cv[n], ys);
            }
        }
        const float z = xz[(size_t)t * (2 * EDIM) + EDIM + e];
        const float yv = ys + Dv * x;
        y[(size_t)t * EDIM + e] = f2bf(yv * (z / (1.f + __expf(-z))));
    }
}

extern "C" void kernel_launch(void* const* d_in, const int* in_sizes, int n_in,
                              void* d_out, int out_size, void* d_ws, size_t ws_size,
                              hipStream_t stream) {
    const int*   ids   = (const int*)d_in[0];
    const float* emb   = (const float*)d_in[1];
    const float* inW   = (const float*)d_in[2];
    const float* convW = (const float*)d_in[3];
    const float* convB = (const float*)d_in[4];
    const float* xpW   = (const float*)d_in[5];
    const float* dtW   = (const float*)d_in[6];
    const float* dtB   = (const float*)d_in[7];
    const float* Alog  = (const float*)d_in[8];
    const float* Dpar  = (const float*)d_in[9];
    const float* outW  = (const float*)d_in[10];
    const float* normW = (const float*)d_in[11];
    const float* normF = (const float*)d_in[12];
    const float* headW = (const float*)d_in[13];
    float* out = (float*)d_out;

    // ---- workspace layout (~210 MB, r7-identical) ----
    float* ws    = (float*)d_ws;
    float* res   = ws;                                      // L*D
    float* xzb   = res   + (size_t)LSEQ * DMODEL;           // L*2E
    float* xcb   = xzb   + (size_t)LSEQ * 2 * EDIM;         // L*E
    float* dbcb  = xcb   + (size_t)LSEQ * EDIM;             // L*96
    float* dtb   = dbcb  + (size_t)LSEQ * 96;               // L*E
    float* xob   = dtb   + (size_t)LSEQ * EDIM;             // L*D
    float* hpart = xob   + (size_t)LSEQ * DMODEL;           // NCHUNK*E*NST
    float* sdtb  = hpart + (size_t)NCHUNK * EDIM * NST;     // NCHUNK*E
    u16* hbf  = (u16*)(sdtb + (size_t)NCHUNK * EDIM);       // L*D   bf16
    u16* ybf  = hbf  + (size_t)LSEQ * DMODEL;               // L*E   bf16
    u16* wbf  = ybf  + (size_t)LSEQ * EDIM;                 // NPADV*D bf16 scratch (head)
    u16* wbf2 = wbf  + (size_t)2 * EDIM * DMODEL;           // out_w slot
    // layer-lifetime buffers carved from the unused tail of the head scratch:
    u16* xc16  = wbf  + (size_t)12 * 1024 * 1024;           // L*E bf16
    u16* dbc16 = xc16 + (size_t)LSEQ * EDIM;                // L*64 bf16
    u16* xpw16 = dbc16 + (size_t)LSEQ * DTRANK;             // 96*E bf16
    u16* dtw16 = xpw16 + (size_t)96 * EDIM;                 // E*64 bf16

    k_embed<<<LSEQ, 256, 0, stream>>>(ids, emb, res);

    for (int i = 0; i < NLAYER; ++i) {
        if (i == 0)
            k_addnorm<false><<<LSEQ, 256, 0, stream>>>(res, nullptr, normW, hbf);
        else
            k_addnorm<true><<<LSEQ, 256, 0, stream>>>(res, xob, normW + (size_t)i * DMODEL, hbf);

        // convert this layer's weights to bf16 (in_w, out_w, xp_w, dt_w)
        k_cvtL<<<4096, 256, 0, stream>>>(
            inW  + (size_t)i * 2 * EDIM * DMODEL, wbf,   (long long)2 * EDIM * DMODEL,
            outW + (size_t)i * DMODEL * EDIM,     wbf2,  (long long)DMODEL * EDIM,
            xpW  + (size_t)i * 96 * EDIM,         xpw16, (long long)96 * EDIM,
            dtW  + (size_t)i * EDIM * DTRANK,     dtw16, (long long)EDIM * DTRANK);

        // xz = h @ in_w^T : (2048 x 4096), K=1024 — NBUF=3, per-wave epilogue
        k_gemm128<16, 0, false, 3, false><<<dim3(512), 256, 0, stream>>>(hbf, wbf, xzb,
                nullptr, 2 * EDIM, DMODEL, 2 * EDIM, 64);

        k_conv<<<dim3(8, 256), 256, 0, stream>>>(xzb, convW + (size_t)i * EDIM * 4,
                convB + (size_t)i * EDIM, xcb, xc16);

        // dbc = xc @ xp_w^T : (2048 x 96), K=2048  (bf16 in, fp32 + bf16 out)
        k_xproj<<<128, 256, 0, stream>>>(xc16, xpw16, dbcb, dbc16);

        // dt = softplus(dbc16 @ dt_w^T + dt_b) : (2048 x 2048), K=64
        k_gemm128<16, 1, false, 3, false><<<dim3(256), 256, 0, stream>>>(dbc16, dtw16, dtb,
                dtB + (size_t)i * EDIM, EDIM, DTRANK, EDIM, 32);

        const float* Al = Alog + (size_t)i * EDIM * NST;
        k_scanA<<<dim3(NCHUNK, EDIM / 256), 256, 0, stream>>>(dtb, xcb, dbcb, Al, hpart, sdtb);
        k_scanB<<<(EDIM * NST) / 256, 256, 0, stream>>>(hpart, sdtb, Al);
        k_scanC<<<dim3(NCHUNK, EDIM / 256), 256, 0, stream>>>(dtb, xcb, dbcb, xzb, Al,
                Dpar + (size_t)i * EDIM, hpart, ybf);

        // x = y @ out_w^T : (2048 x 1024), K=2048 — pipelined 64² tile, grid 512
        k_gemm64<32><<<dim3(512), 256, 0, stream>>>(ybf, wbf2, xob,
                DMODEL, EDIM, DMODEL, 64);
    }

    k_addnorm<true><<<LSEQ, 256, 0, stream>>>(res, xob, normF, hbf);

    // head: convert W (padded to 50304 rows, zeros), then 128² GEMM
    // grid = 16*393 = 6288 (%8==0), ~24/CU -> NBUF=2 (4 blocks/CU), coop+NT stores
    k_cvt<<<4096, 256, 0, stream>>>(headW, wbf,
            (long long)NVOCAB * DMODEL, (long long)NPADV * DMODEL);
    k_gemm128<16, 0, true, 2, true><<<dim3(6288), 256, 0, stream>>>(hbf, wbf, out, nullptr,
            NVOCAB, DMODEL, NVOCAB, 6288 / 8);
}